// Round 5
// baseline (915.148 us; speedup 1.0000x reference)
//
#include <hip/hip_runtime.h>

#define TPB 256
constexpr int HID = 16;
constexpr int NC  = 8;
constexpr int B3  = 256;      // blocks for edge-chunk passes (p1/p3)
constexpr int BSH = 7;        // 128 nodes per bucket
constexpr int BNODES = 128;
constexpr int NBMAX = 1024;   // max buckets (N <= 131072)
constexpr int SSPLIT = 4;     // sub-blocks per bucket in pull/deg passes
constexpr int P1S = 17;       // padded LDS stride pull1 (breaks even-offset bank clustering)
constexpr int P2S = 9;        // padded LDS stride pull2

__device__ __forceinline__ void atomAddF(float* p, float v) {
    unsafeAtomicAdd(p, v);    // native global_atomic_add_f32
}

__device__ __forceinline__ unsigned short f2bf(float f) {   // RNE float->bf16
    union { float f; unsigned u; } a; a.f = f;
    unsigned r = a.u + 0x7FFF + ((a.u >> 16) & 1);
    return (unsigned short)(r >> 16);
}
__device__ __forceinline__ float bf2f(unsigned s) {
    union { unsigned u; float f; } b; b.u = s << 16; return b.f;
}

// Detect whether edge_index arrived as int64 (odd 32-bit words all zero) or int32.
__global__ void detect64_kernel(const int* __restrict__ ei, int E, int* flag) {
    int l = threadIdx.x;
    int v = 0;
    if (l < 32 && 2 * l + 1 < 2 * E) v = ei[2 * l + 1];
    unsigned long long b = __ballot(v != 0);
    if (l == 0) *flag = (b == 0ULL) ? 1 : 0;
}

__device__ __forceinline__ int edge_at(const int* __restrict__ ei, int index, int is64) {
    return is64 ? ei[2 * index] : ei[index];
}

// ---------------- P1: per-(bucket,block) edge counts via LDS histogram ----------------
__global__ __launch_bounds__(TPB) void p1_count_kernel(const int* __restrict__ ei, int* __restrict__ cnts,
                                                       int E, int NB, const int* __restrict__ flag) {
    __shared__ int h[NBMAX];
    int t = threadIdx.x;
    for (int i = t; i < NB; i += TPB) h[i] = 0;
    __syncthreads();
    int is64 = *flag;
    int chunk = (E + B3 - 1) / B3;
    int beg = blockIdx.x * chunk;
    int end = min(E, beg + chunk);
    for (int e = beg + t; e < end; e += TPB) {
        int dst = edge_at(ei, E + e, is64);
        atomicAdd(&h[dst >> BSH], 1);   // LDS atomic
    }
    __syncthreads();
    for (int i = t; i < NB; i += TPB) cnts[i * B3 + blockIdx.x] = h[i];
}

// ---------------- exclusive scan of M counts ----------------
__global__ void scan1_kernel(const int* __restrict__ a, int* bsum, int M) {
    __shared__ int sd[256];
    int t = threadIdx.x;
    int base = blockIdx.x * 1024 + t * 4;
    int s = 0;
#pragma unroll
    for (int q = 0; q < 4; ++q) if (base + q < M) s += a[base + q];
    sd[t] = s; __syncthreads();
    for (int off = 128; off >= 1; off >>= 1) {
        if (t < off) sd[t] += sd[t + off];
        __syncthreads();
    }
    if (t == 0) bsum[blockIdx.x] = sd[0];
}

__global__ void scan2_kernel(int* bsum, int nb) {
    __shared__ int sd[256];
    int t = threadIdx.x;
    int base = t * 4;
    int v0 = base + 0 < nb ? bsum[base + 0] : 0;
    int v1 = base + 1 < nb ? bsum[base + 1] : 0;
    int v2 = base + 2 < nb ? bsum[base + 2] : 0;
    int v3 = base + 3 < nb ? bsum[base + 3] : 0;
    int s = v0 + v1 + v2 + v3;
    sd[t] = s; __syncthreads();
    for (int off = 1; off < 256; off <<= 1) {
        int val = 0;
        if (t >= off) val = sd[t - off];
        __syncthreads();
        if (t >= off) sd[t] += val;
        __syncthreads();
    }
    int e = sd[t] - s;
    if (base + 0 < nb) bsum[base + 0] = e;           e += v0;
    if (base + 1 < nb) bsum[base + 1] = e;           e += v1;
    if (base + 2 < nb) bsum[base + 2] = e;           e += v2;
    if (base + 3 < nb) bsum[base + 3] = e;
}

__global__ void scan3_kernel(int* a, const int* __restrict__ bsum, int M) {
    __shared__ int sd[256];
    int t = threadIdx.x;
    int base = blockIdx.x * 1024 + t * 4;
    int v0 = 0, v1 = 0, v2 = 0, v3 = 0;
    if (base + 0 < M) v0 = a[base + 0];
    if (base + 1 < M) v1 = a[base + 1];
    if (base + 2 < M) v2 = a[base + 2];
    if (base + 3 < M) v3 = a[base + 3];
    int s = v0 + v1 + v2 + v3;
    sd[t] = s; __syncthreads();
    for (int off = 1; off < 256; off <<= 1) {
        int val = 0;
        if (t >= off) val = sd[t - off];
        __syncthreads();
        if (t >= off) sd[t] += val;
        __syncthreads();
    }
    int excl = sd[t] - s + bsum[blockIdx.x];
    int e0 = excl, e1 = e0 + v0, e2 = e1 + v1, e3 = e2 + v2;
    if (base + 0 < M) a[base + 0] = e0;
    if (base + 1 < M) a[base + 1] = e1;
    if (base + 2 < M) a[base + 2] = e2;
    if (base + 3 < M) a[base + 3] = e3;
}

// ---------------- P3: scatter edges into bucket-major segments (LDS cursors) ----------------
__global__ __launch_bounds__(TPB) void p3_scatter_kernel(const int* __restrict__ ei, const float* __restrict__ w,
                                                         const int* __restrict__ scn, int2* __restrict__ payload,
                                                         int E, int NB, const int* __restrict__ flag) {
    __shared__ int cur[NBMAX];
    int t = threadIdx.x;
    for (int i = t; i < NB; i += TPB) cur[i] = scn[i * B3 + blockIdx.x];
    __syncthreads();
    int is64 = *flag;
    int chunk = (E + B3 - 1) / B3;
    int beg = blockIdx.x * chunk;
    int end = min(E, beg + chunk);
    for (int e = beg + t; e < end; e += TPB) {
        int src = edge_at(ei, e, is64);
        int dst = edge_at(ei, E + e, is64);
        int b = dst >> BSH;
        int p = atomicAdd(&cur[b], 1);   // LDS atomic
        payload[p] = make_int2(src | ((dst & (BNODES - 1)) << 20), __float_as_int(w[e]));
    }
}

// dis = 1.0 (self-loop weight)
__global__ void init_dis_kernel(float* dis, int N) {
    int i = blockIdx.x * TPB + threadIdx.x;
    if (i < N) dis[i] = 1.0f;
}

// ---------------- P4: per-(bucket,sub) weighted degree partials -> global atomics ----------------
__global__ __launch_bounds__(TPB) void p4_deg_kernel(const int2* __restrict__ payload,
                                                     const int* __restrict__ scn,
                                                     float* __restrict__ dis, int E, int N, int NB) {
    __shared__ float degs[BNODES];
    int t = threadIdx.x;
    if (t < BNODES) degs[t] = 0.f;
    __syncthreads();
    int b = blockIdx.x >> 2, s = blockIdx.x & (SSPLIT - 1);
    int bbeg = scn[b * B3];
    int bend = (b + 1 < NB) ? scn[(b + 1) * B3] : E;
    int cntb = bend - bbeg;
    int per  = (cntb + SSPLIT - 1) / SSPLIT;
    int sbeg = bbeg + s * per;
    int send = min(bend, sbeg + per);
    for (int p = sbeg + t; p < send; p += TPB) {
        int2 r = payload[p];
        atomicAdd(&degs[(r.x >> 20) & (BNODES - 1)], __int_as_float(r.y));  // LDS f32
    }
    __syncthreads();
    if (t < BNODES) {
        int node = (b << BSH) + t;
        if (node < N && degs[t] != 0.f) atomAddF(&dis[node], degs[t]);
    }
}

__global__ void rsqrt_kernel(float* dis, int N) {
    int i = blockIdx.x * TPB + threadIdx.x;
    if (i < N) dis[i] = rsqrtf(dis[i]);
}

// ---------------- gemm1: h1b = bf16( dis * (x @ W1) ), LDS-tiled coalesced ----------------
constexpr int GR  = 256;
constexpr int KT  = 32;
constexpr int LDP = 33;
__global__ __launch_bounds__(256) void gemm1_kernel(const float* __restrict__ x,
                                                    const float* __restrict__ W,
                                                    const float* __restrict__ dis,
                                                    unsigned short* __restrict__ h1b, int N, int K) {
    __shared__ float tile[GR * LDP];
    int t = threadIdx.x;
    int row0 = blockIdx.x * GR;
    float acc[HID];
#pragma unroll
    for (int j = 0; j < HID; ++j) acc[j] = 0.f;
    for (int kt = 0; kt < K; kt += KT) {
        __syncthreads();
#pragma unroll
        for (int q = 0; q < 8; ++q) {
            int f  = q * 256 + t;
            int r  = f >> 3;
            int c4 = f & 7;
            int gr = row0 + r;
            if (gr > N - 1) gr = N - 1;
            float4 v = *reinterpret_cast<const float4*>(x + (size_t)gr * K + kt + c4 * 4);
            float* dstp = &tile[r * LDP + c4 * 4];
            dstp[0] = v.x; dstp[1] = v.y; dstp[2] = v.z; dstp[3] = v.w;
        }
        __syncthreads();
        const float* Wk = W + (size_t)kt * HID;
        const float* lr = &tile[t * LDP];
#pragma unroll
        for (int k = 0; k < KT; ++k) {
            float a = lr[k];
#pragma unroll
            for (int j = 0; j < HID; ++j)
                acc[j] = fmaf(a, Wk[k * HID + j], acc[j]);
        }
    }
    int row = row0 + t;
    if (row < N) {
        float d = dis[row];
        uint4 u0, u1;
        u0.x = f2bf(d*acc[0])  | ((unsigned)f2bf(d*acc[1])  << 16);
        u0.y = f2bf(d*acc[2])  | ((unsigned)f2bf(d*acc[3])  << 16);
        u0.z = f2bf(d*acc[4])  | ((unsigned)f2bf(d*acc[5])  << 16);
        u0.w = f2bf(d*acc[6])  | ((unsigned)f2bf(d*acc[7])  << 16);
        u1.x = f2bf(d*acc[8])  | ((unsigned)f2bf(d*acc[9])  << 16);
        u1.y = f2bf(d*acc[10]) | ((unsigned)f2bf(d*acc[11]) << 16);
        u1.z = f2bf(d*acc[12]) | ((unsigned)f2bf(d*acc[13]) << 16);
        u1.w = f2bf(d*acc[14]) | ((unsigned)f2bf(d*acc[15]) << 16);
        uint4* hr = reinterpret_cast<uint4*>(h1b + (size_t)row * HID);
        hr[0] = u0; hr[1] = u1;
    }
}

// agg1 = b1 + dis * h1b   (self-loop term; pull1 atomically adds the rest)
__global__ void init_agg1_kernel(const unsigned short* __restrict__ h1b, const float* __restrict__ dis,
                                 const float* __restrict__ b1, float* __restrict__ agg1, int N) {
    int t = blockIdx.x * TPB + threadIdx.x;
    if (t >= N * HID) return;
    int i = t >> 4, j = t & 15;
    agg1[t] = b1[j] + dis[i] * bf2f(h1b[t]);
}

// ---------------- pull1: bf16 gathers, 8 lanes/record (ushort2/lane), 8x unroll ----------------
__global__ __launch_bounds__(TPB) void pull1_kernel(const int2* __restrict__ payload,
        const int* __restrict__ scn, const unsigned short* __restrict__ h1b,
        const float* __restrict__ dis, float* __restrict__ agg1, int E, int N, int NB) {
    __shared__ float acc[BNODES * P1S];
    int t = threadIdx.x;
    for (int i = t; i < BNODES * P1S; i += TPB) acc[i] = 0.f;
    __syncthreads();
    int b = blockIdx.x >> 2, s = blockIdx.x & (SSPLIT - 1);
    int bbeg = scn[b * B3];
    int bend = (b + 1 < NB) ? scn[(b + 1) * B3] : E;
    int cntb = bend - bbeg;
    int per  = (cntb + SSPLIT - 1) / SSPLIT;
    int sbeg = bbeg + s * per;
    int send = min(bend, sbeg + per);
    constexpr int G = TPB / 8;            // 32 records in flight per slot
    int rg = t >> 3, jp = t & 7;          // lane handles columns 2jp, 2jp+1
    int p = sbeg + rg;
    for (; p + 7 * G < send; p += 8 * G) {
        int2 r[8]; unsigned g[8];
#pragma unroll
        for (int q = 0; q < 8; ++q) r[q] = payload[p + q * G];
#pragma unroll
        for (int q = 0; q < 8; ++q)
            g[q] = *reinterpret_cast<const unsigned*>(h1b + (size_t)(r[q].x & 0xFFFFF) * HID + 2 * jp);
#pragma unroll
        for (int q = 0; q < 8; ++q) {
            float wq = __int_as_float(r[q].y);
            int dl = (r[q].x >> 20) & (BNODES - 1);
            atomicAdd(&acc[dl * P1S + 2 * jp],     wq * bf2f(g[q] & 0xFFFF));
            atomicAdd(&acc[dl * P1S + 2 * jp + 1], wq * bf2f(g[q] >> 16));
        }
    }
    for (; p < send; p += G) {
        int2 r = payload[p];
        unsigned g = *reinterpret_cast<const unsigned*>(h1b + (size_t)(r.x & 0xFFFFF) * HID + 2 * jp);
        float wq = __int_as_float(r.y);
        int dl = (r.x >> 20) & (BNODES - 1);
        atomicAdd(&acc[dl * P1S + 2 * jp],     wq * bf2f(g & 0xFFFF));
        atomicAdd(&acc[dl * P1S + 2 * jp + 1], wq * bf2f(g >> 16));
    }
    __syncthreads();
    int node0 = b << BSH;
#pragma unroll
    for (int q = 0; q < (BNODES * HID) / TPB; ++q) {
        int idx = q * TPB + t;
        int nl = idx >> 4, jj = idx & 15;
        int node = node0 + nl;
        if (node < N) {
            float v = acc[nl * P1S + jj];
            if (v != 0.f) atomAddF(&agg1[(size_t)node * HID + jj], dis[node] * v);
        }
    }
}

// ---------------- gemm2: h2b = bf16( dis * (relu(agg1) @ W2) ) ----------------
__global__ void gemm2_kernel(const float* __restrict__ agg1, const float* __restrict__ W2,
                             const float* __restrict__ dis, unsigned short* __restrict__ h2b, int N) {
    int i = blockIdx.x * TPB + threadIdx.x;
    if (i >= N) return;
    const float* a = agg1 + (size_t)i * HID;
    float hv[HID];
#pragma unroll
    for (int k = 0; k < HID; k += 4) {
        float4 v = *reinterpret_cast<const float4*>(a + k);
        hv[k]     = fmaxf(v.x, 0.f);
        hv[k + 1] = fmaxf(v.y, 0.f);
        hv[k + 2] = fmaxf(v.z, 0.f);
        hv[k + 3] = fmaxf(v.w, 0.f);
    }
    float acc[NC];
#pragma unroll
    for (int c = 0; c < NC; ++c) acc[c] = 0.f;
#pragma unroll
    for (int k = 0; k < HID; ++k)
#pragma unroll
        for (int c = 0; c < NC; ++c)
            acc[c] = fmaf(hv[k], W2[k * NC + c], acc[c]);
    float d = dis[i];
    uint4 u;
    u.x = f2bf(d*acc[0]) | ((unsigned)f2bf(d*acc[1]) << 16);
    u.y = f2bf(d*acc[2]) | ((unsigned)f2bf(d*acc[3]) << 16);
    u.z = f2bf(d*acc[4]) | ((unsigned)f2bf(d*acc[5]) << 16);
    u.w = f2bf(d*acc[6]) | ((unsigned)f2bf(d*acc[7]) << 16);
    *reinterpret_cast<uint4*>(h2b + (size_t)i * NC) = u;
}

// out = b2 + dis * h2b  (self-loop; pull2 atomically adds the rest; lsm finishes)
__global__ void init_out_kernel(const unsigned short* __restrict__ h2b, const float* __restrict__ dis,
                                const float* __restrict__ b2, float* __restrict__ out, int N) {
    int t = blockIdx.x * TPB + threadIdx.x;
    if (t >= N * NC) return;
    int i = t >> 3, j = t & 7;
    out[t] = b2[j] + dis[i] * bf2f(h2b[t]);
}

// ---------------- pull2: bf16 gathers, 4 lanes/record (ushort2/lane), 8x unroll ----------------
__global__ __launch_bounds__(TPB) void pull2_kernel(const int2* __restrict__ payload,
        const int* __restrict__ scn, const unsigned short* __restrict__ h2b,
        const float* __restrict__ dis, float* __restrict__ out, int E, int N, int NB) {
    __shared__ float acc[BNODES * P2S];
    int t = threadIdx.x;
    for (int i = t; i < BNODES * P2S; i += TPB) acc[i] = 0.f;
    __syncthreads();
    int b = blockIdx.x >> 2, s = blockIdx.x & (SSPLIT - 1);
    int bbeg = scn[b * B3];
    int bend = (b + 1 < NB) ? scn[(b + 1) * B3] : E;
    int cntb = bend - bbeg;
    int per  = (cntb + SSPLIT - 1) / SSPLIT;
    int sbeg = bbeg + s * per;
    int send = min(bend, sbeg + per);
    constexpr int G = TPB / 4;            // 64 records in flight per slot
    int rg = t >> 2, jp = t & 3;          // lane handles classes 2jp, 2jp+1
    int p = sbeg + rg;
    for (; p + 7 * G < send; p += 8 * G) {
        int2 r[8]; unsigned g[8];
#pragma unroll
        for (int q = 0; q < 8; ++q) r[q] = payload[p + q * G];
#pragma unroll
        for (int q = 0; q < 8; ++q)
            g[q] = *reinterpret_cast<const unsigned*>(h2b + (size_t)(r[q].x & 0xFFFFF) * NC + 2 * jp);
#pragma unroll
        for (int q = 0; q < 8; ++q) {
            float wq = __int_as_float(r[q].y);
            int dl = (r[q].x >> 20) & (BNODES - 1);
            atomicAdd(&acc[dl * P2S + 2 * jp],     wq * bf2f(g[q] & 0xFFFF));
            atomicAdd(&acc[dl * P2S + 2 * jp + 1], wq * bf2f(g[q] >> 16));
        }
    }
    for (; p < send; p += G) {
        int2 r = payload[p];
        unsigned g = *reinterpret_cast<const unsigned*>(h2b + (size_t)(r.x & 0xFFFFF) * NC + 2 * jp);
        float wq = __int_as_float(r.y);
        int dl = (r.x >> 20) & (BNODES - 1);
        atomicAdd(&acc[dl * P2S + 2 * jp],     wq * bf2f(g & 0xFFFF));
        atomicAdd(&acc[dl * P2S + 2 * jp + 1], wq * bf2f(g >> 16));
    }
    __syncthreads();
    int node0 = b << BSH;
#pragma unroll
    for (int q = 0; q < (BNODES * NC) / TPB; ++q) {
        int idx = q * TPB + t;
        int nl = idx >> 3, jj = idx & 7;
        int node = node0 + nl;
        if (node < N) {
            float v = acc[nl * P2S + jj];
            if (v != 0.f) atomAddF(&out[(size_t)node * NC + jj], dis[node] * v);
        }
    }
}

// in-place log_softmax over 8 classes, one row per thread
__global__ void lsm_kernel(float* __restrict__ out, int N) {
    int i = blockIdx.x * TPB + threadIdx.x;
    if (i >= N) return;
    float* r = out + (size_t)i * NC;
    float4 a = *reinterpret_cast<const float4*>(r);
    float4 b = *reinterpret_cast<const float4*>(r + 4);
    float v[NC] = {a.x, a.y, a.z, a.w, b.x, b.y, b.z, b.w};
    float m = v[0];
#pragma unroll
    for (int j = 1; j < NC; ++j) m = fmaxf(m, v[j]);
    float s = 0.f;
#pragma unroll
    for (int j = 0; j < NC; ++j) s += __expf(v[j] - m);
    float lse = m + __logf(s);
#pragma unroll
    for (int j = 0; j < NC; ++j) v[j] -= lse;
    *reinterpret_cast<float4*>(r)     = make_float4(v[0], v[1], v[2], v[3]);
    *reinterpret_cast<float4*>(r + 4) = make_float4(v[4], v[5], v[6], v[7]);
}

// ---------------- fallback push-atomic kernels (only if ws too small) ----------------
__global__ void fb_deg_edge(const int* __restrict__ ei, const float* __restrict__ w,
                            float* deg, int E, const int* __restrict__ flag) {
    int e = blockIdx.x * TPB + threadIdx.x;
    if (e >= E) return;
    int is64 = *flag;
    atomAddF(&deg[edge_at(ei, E + e, is64)], w[e]);
}
__global__ void fb_edge1(const int* __restrict__ ei, const float* __restrict__ w,
                         const float* __restrict__ dis, const unsigned short* __restrict__ h1b,
                         float* __restrict__ agg1, int E, const int* __restrict__ flag) {
    int t = blockIdx.x * TPB + threadIdx.x;
    if (t >= E * HID) return;
    int e = t >> 4, j = t & 15;
    int is64 = *flag;
    int src = edge_at(ei, e, is64);
    int dst = edge_at(ei, E + e, is64);
    atomAddF(&agg1[dst * HID + j], w[e] * dis[dst] * bf2f(h1b[src * HID + j]));
}
__global__ void fb_edge2(const int* __restrict__ ei, const float* __restrict__ w,
                         const float* __restrict__ dis, const unsigned short* __restrict__ h2b,
                         float* __restrict__ out, int E, const int* __restrict__ flag) {
    int t = blockIdx.x * TPB + threadIdx.x;
    if (t >= E * NC) return;
    int e = t >> 3, j = t & 7;
    int is64 = *flag;
    int src = edge_at(ei, e, is64);
    int dst = edge_at(ei, E + e, is64);
    atomAddF(&out[dst * NC + j], w[e] * dis[dst] * bf2f(h2b[src * NC + j]));
}

extern "C" void kernel_launch(void* const* d_in, const int* in_sizes, int n_in,
                              void* d_out, int out_size, void* d_ws, size_t ws_size,
                              hipStream_t stream) {
    const float* x  = (const float*)d_in[0];
    const int*   ei = (const int*)d_in[1];
    const float* w  = (const float*)d_in[2];
    const float* W1 = (const float*)d_in[3];
    const float* b1 = (const float*)d_in[4];
    const float* W2 = (const float*)d_in[5];
    const float* b2 = (const float*)d_in[6];
    float* out = (float*)d_out;

    int E = in_sizes[2];          // 3,200,000
    int N = out_size / NC;        // 100,000
    int K = in_sizes[0] / N;      // 512

    int NB   = (N + BNODES - 1) >> BSH;   // 782 buckets
    int M    = NB * B3;                   // 200,192 counts
    int nblk = (M + 1023) / 1024;         // 196

    // workspace layout, all chunks 16B-aligned
    char* wp = (char*)d_ws;
    auto take = [&wp](size_t bytes) { char* r = wp; wp += (bytes + 15) & ~(size_t)15; return r; };
    int2*  payload = (int2*)take((size_t)E * 8);
    float* dis  = (float*)take((size_t)N * 4);
    unsigned short* h1b = (unsigned short*)take((size_t)N * HID * 2);
    float* agg1 = (float*)take((size_t)N * HID * 4);
    unsigned short* h2b = (unsigned short*)take((size_t)N * NC * 2);
    int*   cnts = (int*)take((size_t)M * 4);
    int*   bsum = (int*)take(1024 * 4);
    int*   flag = (int*)take(16);
    size_t need = (size_t)(wp - (char*)d_ws);

    auto nb = [](long long n) { return (int)((n + TPB - 1) / TPB); };

    if (ws_size >= need && NB <= NBMAX && nblk <= 1024 && N < (1 << 20)) {
        detect64_kernel<<<1, 64, 0, stream>>>(ei, E, flag);
        p1_count_kernel<<<B3, TPB, 0, stream>>>(ei, cnts, E, NB, flag);
        scan1_kernel<<<nblk, 256, 0, stream>>>(cnts, bsum, M);
        scan2_kernel<<<1, 256, 0, stream>>>(bsum, nblk);
        scan3_kernel<<<nblk, 256, 0, stream>>>(cnts, bsum, M);
        p3_scatter_kernel<<<B3, TPB, 0, stream>>>(ei, w, cnts, payload, E, NB, flag);
        init_dis_kernel<<<nb(N), TPB, 0, stream>>>(dis, N);
        p4_deg_kernel<<<NB * SSPLIT, TPB, 0, stream>>>(payload, cnts, dis, E, N, NB);
        rsqrt_kernel<<<nb(N), TPB, 0, stream>>>(dis, N);
        gemm1_kernel<<<(N + GR - 1) / GR, 256, 0, stream>>>(x, W1, dis, h1b, N, K);
        init_agg1_kernel<<<nb((long long)N * HID), TPB, 0, stream>>>(h1b, dis, b1, agg1, N);
        pull1_kernel<<<NB * SSPLIT, TPB, 0, stream>>>(payload, cnts, h1b, dis, agg1, E, N, NB);
        gemm2_kernel<<<nb(N), TPB, 0, stream>>>(agg1, W2, dis, h2b, N);
        init_out_kernel<<<nb((long long)N * NC), TPB, 0, stream>>>(h2b, dis, b2, out, N);
        pull2_kernel<<<NB * SSPLIT, TPB, 0, stream>>>(payload, cnts, h2b, dis, out, E, N, NB);
        lsm_kernel<<<nb(N), TPB, 0, stream>>>(out, N);
    } else {
        // fallback: push atomics (bf16 features, dis folded into h')
        char* fp = (char*)d_ws;
        auto ftake = [&fp](size_t bytes) { char* r = fp; fp += (bytes + 15) & ~(size_t)15; return r; };
        float* fdis = (float*)ftake((size_t)N * 4);
        unsigned short* fh1 = (unsigned short*)ftake((size_t)N * HID * 2);
        float* fagg = (float*)ftake((size_t)N * HID * 4);
        unsigned short* fh2 = (unsigned short*)ftake((size_t)N * NC * 2);
        int*   ffl  = (int*)ftake(16);
        detect64_kernel<<<1, 64, 0, stream>>>(ei, E, ffl);
        init_dis_kernel<<<nb(N), TPB, 0, stream>>>(fdis, N);
        fb_deg_edge<<<nb(E), TPB, 0, stream>>>(ei, w, fdis, E, ffl);
        rsqrt_kernel<<<nb(N), TPB, 0, stream>>>(fdis, N);
        gemm1_kernel<<<(N + GR - 1) / GR, 256, 0, stream>>>(x, W1, fdis, fh1, N, K);
        init_agg1_kernel<<<nb((long long)N * HID), TPB, 0, stream>>>(fh1, fdis, b1, fagg, N);
        fb_edge1<<<nb((long long)E * HID), TPB, 0, stream>>>(ei, w, fdis, fh1, fagg, E, ffl);
        gemm2_kernel<<<nb(N), TPB, 0, stream>>>(fagg, W2, fdis, fh2, N);
        init_out_kernel<<<nb((long long)N * NC), TPB, 0, stream>>>(fh2, fdis, b2, out, N);
        fb_edge2<<<nb((long long)E * NC), TPB, 0, stream>>>(ei, w, fdis, fh2, out, E, ffl);
        lsm_kernel<<<nb(N), TPB, 0, stream>>>(out, N);
    }
}